// Round 5
// baseline (210.722 us; speedup 1.0000x reference)
//
#include <hip/hip_runtime.h>

#define B_ 64
#define C_ 3
#define H_ 384
#define W_ 384
#define HW_ (H_ * W_)
#define TOTALF ((size_t)B_ * C_ * HW_)

// Output tile per block: 64 wide x 8 tall, 256 threads, 2 vertical px/thread.
#define TW 64
#define TH 8
// Staged input region budget (block-uniform, from affine corner extrema):
// typical NR ~ 8*1.05 + 64*0.05 + 2 ~ 14, NC ~ 64*1.05 + 8*0.05 + 2 ~ 70.
// Budget covers ~4 sigma of theta noise; beyond that -> exact global fallback.
#define NRMAX 24
#define NCMAX 84      // includes up-to-3 cols of 16B-alignment padding
#define NWMAX 21      // NCMAX/4 dwordx4 chunks per row

typedef float f32x4 __attribute__((ext_vector_type(4)));
typedef float f32x2 __attribute__((ext_vector_type(2)));
typedef f32x2 __attribute__((aligned(4))) f32x2_u;

// Theory: kernel is bound by TCP processing of SCATTERED gather requests
// (~10 distinct lines per pair-gather instr; R4 confirmed instr-count lever).
// Stage the tile's input region into LDS with sequential dwordx4 loads, then
// gather from LDS: VMEM side becomes pure coalesced streaming.
__global__ __launch_bounds__(256) void affine_sample_kernel(
    const float* __restrict__ imgs,
    const float* __restrict__ theta,
    float* __restrict__ out)
{
    __shared__ float smem[C_][NRMAX][NCMAX];   // 24,192 B -> 6 blocks/CU

    // XCD swizzle: 18,432 blocks / 8 XCDs = 2,304 per XCD = 8 whole images.
    int nb = gridDim.x;
    int bid = blockIdx.x;
    int sb = (bid & 7) * (nb >> 3) + (bid >> 3);

    // Per image: 48 row-tiles x 6 col-tiles = 288 blocks, xt fastest.
    int b   = sb / 288;
    int rem = sb - b * 288;
    int yt  = rem / 6;
    int xt  = rem - yt * 6;
    b = __builtin_amdgcn_readfirstlane(b);

    const float* th = theta + b * 6;
    float t00 = th[0], t01 = th[1], t02 = th[2];
    float t10 = th[3], t11 = th[4], t12 = th[5];

    // ---- block-uniform staging region from the 4 tile corners ----
    float xgl = (float)(xt * TW) - 191.5f;
    float xgr = xgl + (float)(TW - 1);
    float ygt = (float)(yt * TH) - 191.5f;
    float ygb = ygt + (float)(TH - 1);

    float ix00 = fmaf(xgl, t00, fmaf(ygt, t01, t02)) + 191.5f;
    float ix10 = fmaf(xgr, t00, fmaf(ygt, t01, t02)) + 191.5f;
    float ix01 = fmaf(xgl, t00, fmaf(ygb, t01, t02)) + 191.5f;
    float ix11 = fmaf(xgr, t00, fmaf(ygb, t01, t02)) + 191.5f;
    float iy00 = fmaf(xgl, t10, fmaf(ygt, t11, t12)) + 191.5f;
    float iy10 = fmaf(xgr, t10, fmaf(ygt, t11, t12)) + 191.5f;
    float iy01 = fmaf(xgl, t10, fmaf(ygb, t11, t12)) + 191.5f;
    float iy11 = fmaf(xgr, t10, fmaf(ygb, t11, t12)) + 191.5f;

    // 0.01 margin >> fma rounding error (<5e-5 at |ix|<400): interior pixels
    // can never floor() outside the staged range.
    float ixmin = fminf(fminf(ix00, ix10), fminf(ix01, ix11)) - 0.01f;
    float ixmax = fmaxf(fmaxf(ix00, ix10), fmaxf(ix01, ix11)) + 0.01f;
    float iymin = fminf(fminf(iy00, iy10), fminf(iy01, iy11)) - 0.01f;
    float iymax = fmaxf(fmaxf(iy00, iy10), fmaxf(iy01, iy11)) + 0.01f;

    // Tap ranges after clamping (pair base xb in [0,W-2]; rows y0,y1 in [0,H-1]).
    int cl  = (int)fminf(fmaxf(floorf(ixmin), 0.0f), (float)(W_ - 2));
    int chp = (int)fminf(fmaxf(floorf(ixmax), 0.0f), (float)(W_ - 2)) + 1;
    int rl  = (int)fminf(fmaxf(floorf(iymin), 0.0f), (float)(H_ - 1));
    int rhi = (int)fminf(fmaxf(floorf(iymax) + 1.0f, 0.0f), (float)(H_ - 1));

    int c0a = cl & ~3;                 // 16B-align staging base
    int NC  = chp - c0a + 1;
    int NR  = rhi - rl + 1;

    c0a = __builtin_amdgcn_readfirstlane(c0a);
    rl  = __builtin_amdgcn_readfirstlane(rl);
    NC  = __builtin_amdgcn_readfirstlane(NC);
    NR  = __builtin_amdgcn_readfirstlane(NR);

    bool accept = (NC <= NCMAX) && (NR <= NRMAX);

    int tid = threadIdx.x;
    int x = xt * TW + (tid & 63);           // lanes = consecutive x, same y
    int y = yt * TH + ((tid >> 6) << 1);    // each thread: rows y, y+1

    const float* bimg = imgs + (size_t)b * (C_ * HW_);
    float* boutbase = out + (size_t)b * (C_ * HW_) + (size_t)y * W_ + x;

    float xg = (float)x - 191.5f;

    if (accept) {
        // ---- stage region: fixed 24x21 chunk grid, 2 chunks/thread/channel ----
        int nw = (NC + 3) >> 2;
#pragma unroll
        for (int c = 0; c < C_; ++c) {
#pragma unroll
            for (int k = 0; k < 2; ++k) {
                int idx  = tid + k * 256;            // 0..511 over 24x21=504
                int row  = idx / NWMAX;              // const divisor 21
                int col4 = idx - row * NWMAX;
                if (row < NR && col4 < nw) {
                    int gr = rl + row;
                    int gc = c0a + col4 * 4;
                    size_t goff = (size_t)b * (C_ * HW_) + (size_t)(c * HW_ + gr * W_ + gc);
                    f32x4 vv;
                    if (goff + 3 < TOTALF) {         // tail overhang guard (abs buffer end only)
                        vv = *reinterpret_cast<const f32x4*>(imgs + goff);
                    } else {
                        vv.x = imgs[goff];
                        vv.y = (goff + 1 < TOTALF) ? imgs[goff + 1] : 0.0f;
                        vv.z = (goff + 2 < TOTALF) ? imgs[goff + 2] : 0.0f;
                        vv.w = 0.0f;
                    }
                    *reinterpret_cast<f32x4*>(&smem[c][row][col4 * 4]) = vv;
                }
            }
        }
        __syncthreads();   // accept is block-uniform

        // ---- 2 output pixels per thread, all taps from LDS ----
#pragma unroll
        for (int pi = 0; pi < 2; ++pi) {
            float yg = (float)(y + pi) - 191.5f;
            float ix = fmaf(xg, t00, fmaf(yg, t01, t02)) + 191.5f;
            float iy = fmaf(xg, t10, fmaf(yg, t11, t12)) + 191.5f;

            float x0f = floorf(ix);
            float y0f = floorf(iy);
            float wx1 = ix - x0f;
            float wy1 = iy - y0f;
            float wx0 = 1.0f - wx1;
            float wy0 = 1.0f - wy1;
            float x1f = x0f + 1.0f;
            float y1f = y0f + 1.0f;

            bool vx0 = (x0f >= 0.0f) && (x0f < (float)W_);
            bool vx1 = (x1f >= 0.0f) && (x1f < (float)W_);
            bool vy0 = (y0f >= 0.0f) && (y0f < (float)H_);
            bool vy1 = (y1f >= 0.0f) && (y1f < (float)H_);

            int x0 = (int)fminf(fmaxf(x0f, 0.0f), (float)(W_ - 1));
            int x1 = (int)fminf(fmaxf(x1f, 0.0f), (float)(W_ - 1));
            int y0 = (int)fminf(fmaxf(y0f, 0.0f), (float)(H_ - 1));
            int y1 = (int)fminf(fmaxf(y1f, 0.0f), (float)(H_ - 1));
            int xb = (int)fminf(fmaxf(x0f, 0.0f), (float)(W_ - 2));

            bool selx0 = (x0 == xb);
            bool selx1 = (x1 == xb);

            float w00 = wx0 * wy0 * ((vx0 && vy0) ? 1.0f : 0.0f);
            float w01 = wx1 * wy0 * ((vx1 && vy0) ? 1.0f : 0.0f);
            float w10 = wx0 * wy1 * ((vx0 && vy1) ? 1.0f : 0.0f);
            float w11 = wx1 * wy1 * ((vx1 && vy1) ? 1.0f : 0.0f);

            int lrT = y0 - rl;
            int lrB = y1 - rl;
            int lc  = xb - c0a;

#pragma unroll
            for (int c = 0; c < C_; ++c) {
                float pTx = smem[c][lrT][lc], pTy = smem[c][lrT][lc + 1];
                float pBx = smem[c][lrB][lc], pBy = smem[c][lrB][lc + 1];
                float v00 = selx0 ? pTx : pTy;
                float v01 = selx1 ? pTx : pTy;
                float v10 = selx0 ? pBx : pBy;
                float v11 = selx1 ? pBx : pBy;
                float r = fmaf(v00, w00, fmaf(v01, w01,
                          fmaf(v10, w10, v11 * w11)));
                boutbase[c * HW_ + pi * W_] = r;
            }
        }
    } else {
        // ---- fallback: exact R4 global pair-gather path (any theta) ----
#pragma unroll
        for (int pi = 0; pi < 2; ++pi) {
            float yg = (float)(y + pi) - 191.5f;
            float ix = fmaf(xg, t00, fmaf(yg, t01, t02)) + 191.5f;
            float iy = fmaf(xg, t10, fmaf(yg, t11, t12)) + 191.5f;

            float x0f = floorf(ix);
            float y0f = floorf(iy);
            float wx1 = ix - x0f;
            float wy1 = iy - y0f;
            float wx0 = 1.0f - wx1;
            float wy0 = 1.0f - wy1;
            float x1f = x0f + 1.0f;
            float y1f = y0f + 1.0f;

            bool vx0 = (x0f >= 0.0f) && (x0f < (float)W_);
            bool vx1 = (x1f >= 0.0f) && (x1f < (float)W_);
            bool vy0 = (y0f >= 0.0f) && (y0f < (float)H_);
            bool vy1 = (y1f >= 0.0f) && (y1f < (float)H_);

            int x0 = (int)fminf(fmaxf(x0f, 0.0f), (float)(W_ - 1));
            int x1 = (int)fminf(fmaxf(x1f, 0.0f), (float)(W_ - 1));
            int y0 = (int)fminf(fmaxf(y0f, 0.0f), (float)(H_ - 1));
            int y1 = (int)fminf(fmaxf(y1f, 0.0f), (float)(H_ - 1));
            int xb = (int)fminf(fmaxf(x0f, 0.0f), (float)(W_ - 2));

            bool selx0 = (x0 == xb);
            bool selx1 = (x1 == xb);

            float w00 = wx0 * wy0 * ((vx0 && vy0) ? 1.0f : 0.0f);
            float w01 = wx1 * wy0 * ((vx1 && vy0) ? 1.0f : 0.0f);
            float w10 = wx0 * wy1 * ((vx0 && vy1) ? 1.0f : 0.0f);
            float w11 = wx1 * wy1 * ((vx1 && vy1) ? 1.0f : 0.0f);

            int oT = y0 * W_ + xb;
            int oB = y1 * W_ + xb;

#pragma unroll
            for (int c = 0; c < C_; ++c) {
                const float* p = bimg + c * HW_;
                f32x2 vt = *reinterpret_cast<const f32x2_u*>(p + oT);
                f32x2 vb = *reinterpret_cast<const f32x2_u*>(p + oB);
                float v00 = selx0 ? vt.x : vt.y;
                float v01 = selx1 ? vt.x : vt.y;
                float v10 = selx0 ? vb.x : vb.y;
                float v11 = selx1 ? vb.x : vb.y;
                float r = fmaf(v00, w00, fmaf(v01, w01,
                          fmaf(v10, w10, v11 * w11)));
                boutbase[c * HW_ + pi * W_] = r;
            }
        }
    }
}

extern "C" void kernel_launch(void* const* d_in, const int* in_sizes, int n_in,
                              void* d_out, int out_size, void* d_ws, size_t ws_size,
                              hipStream_t stream) {
    const float* imgs = (const float*)d_in[0];
    const float* theta = (const float*)d_in[1];
    float* out = (float*)d_out;
    int blocks = B_ * (H_ / TH) * (W_ / TW);   // 64 * 48 * 6 = 18,432
    affine_sample_kernel<<<blocks, 256, 0, stream>>>(imgs, theta, out);
}

// Round 6
// 208.384 us; speedup vs baseline: 1.0112x; 1.0112x over previous
//
#include <hip/hip_runtime.h>

#define B_ 64
#define C_ 3
#define H_ 384
#define W_ 384
#define HW_ (H_ * W_)

// Native clang vectors; align(4) variants because xq is only 4B-aligned
// (gfx950 handles unaligned dwordx4), align(8) for the f32x2 stores (x even).
typedef float f32x4 __attribute__((ext_vector_type(4)));
typedef float f32x2 __attribute__((ext_vector_type(2)));
typedef f32x4 __attribute__((aligned(4))) f32x4_u;
typedef f32x2 __attribute__((aligned(4))) f32x2_u;
typedef f32x2 __attribute__((aligned(8))) f32x2_a8;

__device__ __forceinline__ float sel3(int d, float a, float b, float c) {
    return d == 0 ? a : (d == 1 ? b : c);
}

// Per-pixel bilinear setup — bit-identical math to the verified R4 kernel.
struct PixS {
    float w00, w01, w10, w11;
    int   xb, y0, y1;
    bool  selx0, selx1;
};

__device__ __forceinline__ PixS pix_setup(float ix, float iy)
{
    float x0f = floorf(ix);
    float y0f = floorf(iy);
    float wx1 = ix - x0f;
    float wy1 = iy - y0f;
    float wx0 = 1.0f - wx1;
    float wy0 = 1.0f - wy1;
    float x1f = x0f + 1.0f;
    float y1f = y0f + 1.0f;

    bool vx0 = (x0f >= 0.0f) && (x0f < (float)W_);
    bool vx1 = (x1f >= 0.0f) && (x1f < (float)W_);
    bool vy0 = (y0f >= 0.0f) && (y0f < (float)H_);
    bool vy1 = (y1f >= 0.0f) && (y1f < (float)H_);

    int x0 = (int)fminf(fmaxf(x0f, 0.0f), (float)(W_ - 1));
    int x1 = (int)fminf(fmaxf(x1f, 0.0f), (float)(W_ - 1));
    PixS p;
    p.y0 = (int)fminf(fmaxf(y0f, 0.0f), (float)(H_ - 1));
    p.y1 = (int)fminf(fmaxf(y1f, 0.0f), (float)(H_ - 1));
    p.xb = (int)fminf(fmaxf(x0f, 0.0f), (float)(W_ - 2));
    p.selx0 = (x0 == p.xb);
    p.selx1 = (x1 == p.xb);
    p.w00 = wx0 * wy0 * ((vx0 && vy0) ? 1.0f : 0.0f);
    p.w01 = wx1 * wy0 * ((vx1 && vy0) ? 1.0f : 0.0f);
    p.w10 = wx0 * wy1 * ((vx0 && vy1) ? 1.0f : 0.0f);
    p.w11 = wx1 * wy1 * ((vx1 && vy1) ? 1.0f : 0.0f);
    return p;
}

// 2 horizontal px/thread. Both pixels' 8 taps come from 2 (+1 masked straddle)
// dwordx4 row-loads per channel: 9 gather-instrs + 3 f32x2 stores per 128 px
// vs R4's 12 gathers + 6 stores. Theory: remaining time constant is per-VMEM-
// instruction TA address processing; this cuts wave VMEM instrs 18 -> 12.
__global__ __launch_bounds__(256) void affine_sample_kernel(
    const float* __restrict__ imgs,
    const float* __restrict__ theta,
    float* __restrict__ out)
{
    // XCD swizzle: 18,432 blocks / 8 = 2,304 per XCD = 8 whole images per XCD.
    int nb = gridDim.x;
    int bid = blockIdx.x;
    int sb = (bid & 7) * (nb >> 3) + (bid >> 3);

    // Per image: 96 row-quads x 3 x-tiles (128 px wide) = 288 blocks, xt fastest.
    int b   = sb / 288;
    int rem = sb - b * 288;
    int yt  = rem / 3;
    int xt  = rem - yt * 3;
    b = __builtin_amdgcn_readfirstlane(b);

    int tid = threadIdx.x;
    int x = xt * 128 + ((tid & 63) << 1);   // wave = 128 consecutive x (2/lane)
    int y = yt * 4 + (tid >> 6);            // 4 waves = 4 consecutive rows

    const float* th = theta + b * 6;
    float t00 = th[0], t01 = th[1], t02 = th[2];
    float t10 = th[3], t11 = th[4], t12 = th[5];

    float xg0 = (float)x - 191.5f;
    float xg1 = xg0 + 1.0f;                 // == (float)(x+1)-191.5f exactly
    float yg  = (float)y - 191.5f;

    float ix0 = fmaf(xg0, t00, fmaf(yg, t01, t02)) + 191.5f;
    float iy0 = fmaf(xg0, t10, fmaf(yg, t11, t12)) + 191.5f;
    float ix1 = fmaf(xg1, t00, fmaf(yg, t01, t02)) + 191.5f;
    float iy1 = fmaf(xg1, t10, fmaf(yg, t11, t12)) + 191.5f;

    PixS p0 = pix_setup(ix0, iy0);
    PixS p1 = pix_setup(ix1, iy1);

    // Shared 4-float column window [xq, xq+3] covering both pixels' tap pairs.
    int xq = p0.xb < p1.xb ? p0.xb : p1.xb;
    if (xq > W_ - 4) xq = W_ - 4;
    int d0 = p0.xb - xq;                    // in [0,2] for |t00|<~2
    int d1 = p1.xb - xq;

    // Row coverage: rows {p0.y0, p0.y1} + at most one extra row for px1
    // (|t10|<1 guarantees |y0f_1 - y0f_0| <= 1 -> at most 1 missing row).
    bool needT = (p1.y0 != p0.y0) && (p1.y0 != p0.y1);
    bool needB = (p1.y1 != p0.y1) && (p1.y1 != p0.y0);
    int  rX    = needT ? p1.y0 : p1.y1;
    bool needX = needT || needB;
    // Fast path valid iff column windows fit and <=1 extra row suffices.
    bool ok = (d0 <= 2) && (d1 <= 2) && !(needT && needB && (p1.y1 != p1.y0));

    const float* bimg = imgs + (size_t)b * (C_ * HW_);
    int aoff = p0.y0 * W_ + xq;
    int boff = p0.y1 * W_ + xq;
    int xoff = rX    * W_ + xq;

    // ---- issue all 6 row-loads up front (MLP), then the masked straddle ----
    f32x4 Av[3], Bv[3], Xv[3];
#pragma unroll
    for (int c = 0; c < C_; ++c) {
        Av[c] = *reinterpret_cast<const f32x4_u*>(bimg + c * HW_ + aoff);
        Bv[c] = *reinterpret_cast<const f32x4_u*>(bimg + c * HW_ + boff);
        Xv[c] = Av[c];                      // defined default for !needX lanes
    }
    if (needX) {                            // ~10% of lanes; exec-masked loads
#pragma unroll
        for (int c = 0; c < C_; ++c)
            Xv[c] = *reinterpret_cast<const f32x4_u*>(bimg + c * HW_ + xoff);
    }

    bool selT_A = (p1.y0 == p0.y0);
    bool selT_B = (p1.y0 == p0.y1);
    bool selB_B = (p1.y1 == p0.y1);
    bool selB_A = (p1.y1 == p0.y0);

    float r[2][3];                          // static indices only (unrolled)
#pragma unroll
    for (int c = 0; c < C_; ++c) {
        f32x4 A = Av[c], Bq = Bv[c], X = Xv[c];
        // px0: rows A(top)/B(bottom), column offset d0 — same floats as R4.
        float t0a = sel3(d0, A.x, A.y, A.z),  t0b = sel3(d0, A.y, A.z, A.w);
        float b0a = sel3(d0, Bq.x, Bq.y, Bq.z), b0b = sel3(d0, Bq.y, Bq.z, Bq.w);
        float v00 = p0.selx0 ? t0a : t0b;
        float v01 = p0.selx1 ? t0a : t0b;
        float v10 = p0.selx0 ? b0a : b0b;
        float v11 = p0.selx1 ? b0a : b0b;
        r[0][c] = fmaf(v00, p0.w00, fmaf(v01, p0.w01,
                  fmaf(v10, p0.w10, v11 * p0.w11)));
        // px1: extract column pair from each candidate row, then row-select.
        float eAa = sel3(d1, A.x, A.y, A.z),  eAb = sel3(d1, A.y, A.z, A.w);
        float eBa = sel3(d1, Bq.x, Bq.y, Bq.z), eBb = sel3(d1, Bq.y, Bq.z, Bq.w);
        float eXa = sel3(d1, X.x, X.y, X.z),  eXb = sel3(d1, X.y, X.z, X.w);
        float t1a = selT_A ? eAa : (selT_B ? eBa : eXa);
        float t1b = selT_A ? eAb : (selT_B ? eBb : eXb);
        float b1a = selB_B ? eBa : (selB_A ? eAa : eXa);
        float b1b = selB_B ? eBb : (selB_A ? eAb : eXb);
        float u00 = p1.selx0 ? t1a : t1b;
        float u01 = p1.selx1 ? t1a : t1b;
        float u10 = p1.selx0 ? b1a : b1b;
        float u11 = p1.selx1 ? b1a : b1b;
        r[1][c] = fmaf(u00, p1.w00, fmaf(u01, p1.w01,
                  fmaf(u10, p1.w10, u11 * p1.w11)));
    }

    // Safety net for pathological theta: exact R4 pair-gather recompute.
    if (__builtin_expect(!ok, 0)) {
#pragma unroll
        for (int c = 0; c < C_; ++c) {
            const float* pch = bimg + c * HW_;
            f32x2 vt = *reinterpret_cast<const f32x2_u*>(pch + p0.y0 * W_ + p0.xb);
            f32x2 vb = *reinterpret_cast<const f32x2_u*>(pch + p0.y1 * W_ + p0.xb);
            float v00 = p0.selx0 ? vt.x : vt.y;
            float v01 = p0.selx1 ? vt.x : vt.y;
            float v10 = p0.selx0 ? vb.x : vb.y;
            float v11 = p0.selx1 ? vb.x : vb.y;
            r[0][c] = fmaf(v00, p0.w00, fmaf(v01, p0.w01,
                      fmaf(v10, p0.w10, v11 * p0.w11)));
            f32x2 ut = *reinterpret_cast<const f32x2_u*>(pch + p1.y0 * W_ + p1.xb);
            f32x2 ub = *reinterpret_cast<const f32x2_u*>(pch + p1.y1 * W_ + p1.xb);
            float u00 = p1.selx0 ? ut.x : ut.y;
            float u01 = p1.selx1 ? ut.x : ut.y;
            float u10 = p1.selx0 ? ub.x : ub.y;
            float u11 = p1.selx1 ? ub.x : ub.y;
            r[1][c] = fmaf(u00, p1.w00, fmaf(u01, p1.w01,
                      fmaf(u10, p1.w10, u11 * p1.w11)));
        }
    }

    float* bout = out + (size_t)b * (C_ * HW_) + (size_t)y * W_ + x;
#pragma unroll
    for (int c = 0; c < C_; ++c) {
        f32x2 o; o.x = r[0][c]; o.y = r[1][c];
        *reinterpret_cast<f32x2_a8*>(bout + c * HW_) = o;   // coalesced 8B store
    }
}

extern "C" void kernel_launch(void* const* d_in, const int* in_sizes, int n_in,
                              void* d_out, int out_size, void* d_ws, size_t ws_size,
                              hipStream_t stream) {
    const float* imgs = (const float*)d_in[0];
    const float* theta = (const float*)d_in[1];
    float* out = (float*)d_out;
    int blocks = B_ * 96 * 3;                 // 18,432 (128x4 px tiles)
    affine_sample_kernel<<<blocks, 256, 0, stream>>>(imgs, theta, out);
}